// Round 6
// baseline (80.370 us; speedup 1.0000x reference)
//
#include <hip/hip_runtime.h>
#include <hip/hip_bf16.h>

typedef __bf16 bf16x8 __attribute__((ext_vector_type(8)));
typedef __bf16 bf16x4 __attribute__((ext_vector_type(4)));
typedef float  f32x4  __attribute__((ext_vector_type(4)));

#define MFMA(a, b, c) __builtin_amdgcn_mfma_f32_16x16x32_bf16((a), (b), (c), 0, 0, 0)

__device__ __forceinline__ float sigf(float x)  { return 1.0f / (1.0f + __expf(-x)); }
__device__ __forceinline__ float tanhf_(float x){ return 2.0f / (1.0f + __expf(-2.0f * x)) - 1.0f; }

extern "C" __global__ void __launch_bounds__(512, 2)
traj_disc_kernel(const float* __restrict__ x, const float* __restrict__ dmat,
                 const float* __restrict__ bmat, const float* __restrict__ hmat,
                 const float* __restrict__ mask,
                 const float* __restrict__ emb_w, const float* __restrict__ emb_b,
                 const float* __restrict__ w_ih, const float* __restrict__ w_hh,
                 const float* __restrict__ b_ih, const float* __restrict__ b_hh,
                 const float* __restrict__ e2a_w, const float* __restrict__ e2a_b,
                 const float* __restrict__ dom,
                 const float* __restrict__ sp_w, const float* __restrict__ sp_b,
                 const float* __restrict__ a2e_w, const float* __restrict__ a2e_b,
                 const float* __restrict__ w1, const float* __restrict__ b1,
                 const float* __restrict__ w2, const float* __restrict__ b2,
                 const float* __restrict__ w3, const float* __restrict__ b3,
                 float* __restrict__ out)
{
    const int b0   = blockIdx.x * 2;      // two batches per block
    const int tid  = threadIdx.x;
    const int lane = tid & 63;
    const int w    = tid >> 6;            // wave 0..7
    const int l15  = lane & 15;
    const int lg   = lane >> 4;           // 0..3

    // rows 0-31 = batch0, 32-63 = batch1
    __shared__ __bf16 sAin[64][72];   // 0-15 xe | 16-47 h | 48 ones | 49-63 zero
    __shared__ __bf16 sHl [64][40];
    __shared__ __bf16 sWN [64][40];
    __shared__ __bf16 sHaT[64][40];
    __shared__ __bf16 sEmb[64][40];
    __shared__ __bf16 sPA [64][72];   // 0-31 ha | 32-63 att
    __shared__ float  sMaskT[20][2][36];
    __shared__ float  sDom[144];
    __shared__ __bf16 z1bf[64][136];
    __shared__ __bf16 z2bf[64][136];

    // ---- staging ----
    for (int idx = tid; idx < 64 * 72; idx += 512)
        (&sAin[0][0])[idx] = (idx % 72 == 48) ? (__bf16)1.0f : (__bf16)0.0f;
    for (int idx = tid; idx < 1280; idx += 512) {
        int tt = idx >> 6, r = idx & 63;
        sMaskT[tt][r >> 5][r & 31] = mask[((b0 + (r >> 5)) * 32 + (r & 31)) * 20 + tt];
    }
    if (tid < 144) sDom[tid] = dom[tid];

    // phase-A per-thread constants (i0 covers 64 rows = 2 batches)
    const int i0 = tid >> 3, p0 = tid & 7;
    const int wbA = i0 >> 5, iA = i0 & 31;
    const int bbA = b0 + wbA;
    const float ewa0 = emb_w[2 * p0],      ewa1 = emb_w[2 * p0 + 1];
    const float ewb0 = emb_w[16 + 2 * p0], ewb1 = emb_w[16 + 2 * p0 + 1];
    const float eb0  = emb_b[2 * p0],      eb1  = emb_b[2 * p0 + 1];

    // ---- transposed-gates A-fragment: wave owns gate col-tile w (c = 16w+l15, gate-interleaved c=4h+g) ----
    bf16x8 Ag[2];
    {
        int c  = 16 * w + l15;
        int cg = (c & 3) * 32 + (c >> 2);
        #pragma unroll
        for (int kt = 0; kt < 2; ++kt)
            #pragma unroll
            for (int j = 0; j < 8; ++j) {
                int k = kt * 32 + lg * 8 + j;
                float v;
                if (k < 16)       v = w_ih[k * 128 + cg];
                else if (k < 48)  v = w_hh[(k - 16) * 128 + cg];
                else if (k == 48) v = b_ih[cg] + b_hh[cg];
                else              v = 0.0f;
                Ag[kt][j] = (__bf16)v;
            }
    }
    // CD/EF wave roles: batch wb, row-half mtw, col-half ntw
    const int wb = w >> 2, mtw = (w >> 1) & 1, ntw = w & 1;
    const int cw = ntw * 16 + l15;
    bf16x8 Be2a, Ba2e, Bsp[2][2];
    #pragma unroll
    for (int j = 0; j < 8; ++j) {
        Be2a[j] = (__bf16)e2a_w[(lg * 8 + j) * 32 + cw];
        Ba2e[j] = (__bf16)a2e_w[(lg * 8 + j) * 32 + cw];
    }
    #pragma unroll
    for (int kt = 0; kt < 2; ++kt)
        #pragma unroll
        for (int nt2 = 0; nt2 < 2; ++nt2)
            #pragma unroll
            for (int j = 0; j < 8; ++j)
                Bsp[kt][nt2][j] = (__bf16)sp_w[(kt * 32 + lg * 8 + j) * 32 + nt2 * 16 + l15];
    const float bEw = e2a_b[cw], bAw = a2e_b[cw];
    const float bS2[2] = { sp_b[l15], sp_b[16 + l15] };

    float cst[4] = {0.f, 0.f, 0.f, 0.f};     // cell state per row-tile (2 per batch)
    f32x4 accZ[4] = {};                      // online z1, col-tile w, 4 row-tiles
    bf16x8 Bw1cur, Bw1nxt;
    const int c1 = 16 * w + l15;

    // prefetch t=0 inputs
    float4 pdv, pbv, phv; float px0, px1;
    {
        int base = ((bbA * 32 + iA) * 20 + 0) * 32 + 4 * p0;
        pdv = *(const float4*)(dmat + base);
        pbv = *(const float4*)(bmat + base);
        phv = *(const float4*)(hmat + base);
        int xb = ((bbA * 32 + iA) * 20 + 0) * 2;
        px0 = x[xb]; px1 = x[xb + 1];
    }
    __syncthreads();

    #pragma unroll 1
    for (int t = 0; t < 20; ++t) {
        // ===== phase A: w1 stream, wmat+normalize (regs), wN/xe stores, prefetch t+1 =====
        {
            #pragma unroll
            for (int j = 0; j < 8; ++j)
                Bw1nxt[j] = (__bf16)w1[(t * 32 + lg * 8 + j) * 128 + c1];
            float4 dv = pdv, bv = pbv, hv = phv;
            float xx0 = px0, xx1 = px1;
            if (t < 19) {
                int base = ((bbA * 32 + iA) * 20 + (t + 1)) * 32 + 4 * p0;
                pdv = *(const float4*)(dmat + base);
                pbv = *(const float4*)(bmat + base);
                phv = *(const float4*)(hmat + base);
                int xb = ((bbA * 32 + iA) * 20 + (t + 1)) * 2;
                px0 = x[xb]; px1 = x[xb + 1];
            }
            float4 mj = *(const float4*)&sMaskT[t][wbA][4 * p0];
            float  mi = sMaskT[t][wbA][iA];
            float wq[4];
            #pragma unroll
            for (int q = 0; q < 4; ++q) {
                float bq = (&bv.x)[q], hq = (&hv.x)[q];
                int ib = (int)floorf(bq * (1.0f / 30.0f)); ib = ib < 0 ? 0 : (ib > 11 ? 11 : ib);
                int ih = (int)floorf(hq * (1.0f / 30.0f)); ih = ih < 0 ? 0 : (ih > 11 ? 11 : ih);
                float v = sDom[ib * 12 + ih] - (&dv.x)[q];
                v = v > 0.f ? v : 0.f;
                wq[q] = v * (&mj.x)[q];
            }
            float s = wq[0] + wq[1] + wq[2] + wq[3];
            s += __shfl_xor(s, 1); s += __shfl_xor(s, 2); s += __shfl_xor(s, 4);
            float inv = mi / (mi * s + 1e-8f);
            bf16x4 wn4;
            #pragma unroll
            for (int q = 0; q < 4; ++q) wn4[q] = (__bf16)(wq[q] * inv);
            *(bf16x4*)&sWN[i0][4 * p0] = wn4;
            sAin[i0][2 * p0]     = (__bf16)(xx0 * ewa0 + xx1 * ewb0 + eb0);
            sAin[i0][2 * p0 + 1] = (__bf16)(xx0 * ewa1 + xx1 * ewb1 + eb1);
        }
        __syncthreads();                                   // s1

        // ===== phase B: gates (col-tile w, 4 row-tiles) + lane-local cell + online z1 =====
        {
            bf16x8 az[4], bxh[4][2];
            #pragma unroll
            for (int rt = 0; rt < 4; ++rt) {
                az[rt]     = *(const bf16x8*)&sAin[rt * 16 + l15][16 + lg * 8];
                bxh[rt][0] = *(const bf16x8*)&sAin[rt * 16 + l15][lg * 8];
                bxh[rt][1] = *(const bf16x8*)&sAin[rt * 16 + l15][32 + lg * 8];
            }
            if (t >= 1) {
                #pragma unroll
                for (int rt = 0; rt < 4; ++rt)
                    accZ[rt] = MFMA(az[rt], Bw1cur, accZ[rt]);
            }
            Bw1cur = Bw1nxt;
            #pragma unroll
            for (int rt = 0; rt < 4; ++rt) {
                f32x4 cc = {0.f, 0.f, 0.f, 0.f};
                cc = MFMA(Ag[0], bxh[rt][0], cc);
                cc = MFMA(Ag[1], bxh[rt][1], cc);
                // lane holds i,f,g,o (q=0..3) for n2=rt*16+l15, h=4w+lg
                float cn = sigf(cc[1]) * cst[rt] + sigf(cc[0]) * tanhf_(cc[2]);
                cst[rt] = cn;
                sHl[rt * 16 + l15][4 * w + lg] = (__bf16)(sigf(cc[3]) * tanhf_(cn));
            }
        }
        __syncthreads();                                   // s2

        // ===== phase C+D fused: ha (col-half, both row tiles, x2 dup) then att (intra-wave) =====
        {
            #pragma unroll
            for (int mt = 0; mt < 2; ++mt) {
                bf16x8 a = *(const bf16x8*)&sHl[wb * 32 + mt * 16 + l15][lg * 8];
                f32x4 cc = {0.f, 0.f, 0.f, 0.f};
                cc = MFMA(a, Be2a, cc);
                bf16x4 tv;
                #pragma unroll
                for (int q = 0; q < 4; ++q) {
                    float v = cc[q] + bEw;
                    tv[q] = (__bf16)v;
                    sPA[wb * 32 + mt * 16 + 4 * lg + q][cw] = (__bf16)v;
                }
                *(bf16x4*)&sHaT[wb * 32 + cw][mt * 16 + 4 * lg] = tv;
            }
            // att tile (mtw, ntw): B-frag from own-wave haT writes (in-order LDS)
            bf16x8 aW = *(const bf16x8*)&sWN [wb * 32 + mtw * 16 + l15][lg * 8];
            bf16x8 bT = *(const bf16x8*)&sHaT[wb * 32 + ntw * 16 + l15][lg * 8];
            f32x4 cc = {0.f, 0.f, 0.f, 0.f};
            cc = MFMA(aW, bT, cc);
            #pragma unroll
            for (int q = 0; q < 4; ++q)
                sPA[wb * 32 + mtw * 16 + 4 * lg + q][32 + cw] = (__bf16)cc[q];
        }
        __syncthreads();                                   // s3

        // ===== phase E+F fused: emb row-stripe (both col halves, x2 dup) then h_new (intra-wave) =====
        {
            bf16x8 a0 = *(const bf16x8*)&sPA[wb * 32 + mtw * 16 + l15][lg * 8];
            bf16x8 a1 = *(const bf16x8*)&sPA[wb * 32 + mtw * 16 + l15][32 + lg * 8];
            #pragma unroll
            for (int nt2 = 0; nt2 < 2; ++nt2) {
                f32x4 cc = {0.f, 0.f, 0.f, 0.f};
                cc = MFMA(a0, Bsp[0][nt2], cc);
                cc = MFMA(a1, Bsp[1][nt2], cc);
                #pragma unroll
                for (int q = 0; q < 4; ++q)
                    sEmb[wb * 32 + mtw * 16 + 4 * lg + q][nt2 * 16 + l15] = (__bf16)tanhf_(cc[q] + bS2[nt2]);
            }
            bf16x8 ae = *(const bf16x8*)&sEmb[wb * 32 + mtw * 16 + l15][lg * 8];
            f32x4 cf = {0.f, 0.f, 0.f, 0.f};
            cf = MFMA(ae, Ba2e, cf);
            #pragma unroll
            for (int q = 0; q < 4; ++q)
                sAin[wb * 32 + mtw * 16 + 4 * lg + q][16 + cw] = (__bf16)(cf[q] + bAw);
        }
        // no barrier: next-iteration s1 orders EF -> B(t+1); A(t+1) touches disjoint regions
    }

    // ================= tail =================
    __syncthreads();
    // final z1 accumulate (h_19 with w1 rows 608-639)
    {
        #pragma unroll
        for (int rt = 0; rt < 4; ++rt) {
            bf16x8 az = *(const bf16x8*)&sAin[rt * 16 + l15][16 + lg * 8];
            accZ[rt] = MFMA(az, Bw1cur, accZ[rt]);
        }
    }
    {
        float bias = b1[c1];
        #pragma unroll
        for (int rt = 0; rt < 4; ++rt)
            #pragma unroll
            for (int q = 0; q < 4; ++q) {
                float v = accZ[rt][q] + bias;
                v = v > 0.f ? v : 0.2f * v;
                z1bf[rt * 16 + 4 * lg + q][c1] = (__bf16)v;
            }
    }
    __syncthreads();
    // z2 = leaky(z1 @ w2 + b2): wave owns col-tile w
    {
        f32x4 c2z[4] = {};
        #pragma unroll
        for (int kt = 0; kt < 4; ++kt) {
            bf16x8 bw2;
            #pragma unroll
            for (int j = 0; j < 8; ++j)
                bw2[j] = (__bf16)w2[(kt * 32 + lg * 8 + j) * 128 + c1];
            #pragma unroll
            for (int rt = 0; rt < 4; ++rt) {
                bf16x8 a = *(const bf16x8*)&z1bf[rt * 16 + l15][kt * 32 + lg * 8];
                c2z[rt] = MFMA(a, bw2, c2z[rt]);
            }
        }
        float bias = b2[c1];
        #pragma unroll
        for (int rt = 0; rt < 4; ++rt)
            #pragma unroll
            for (int q = 0; q < 4; ++q) {
                float v = c2z[rt][q] + bias;
                v = v > 0.f ? v : 0.2f * v;
                z2bf[rt * 16 + 4 * lg + q][c1] = (__bf16)v;
            }
    }
    __syncthreads();
    // z3 = sigmoid(z2 @ w3 + b3)
    {
        int n2 = tid >> 3, kg = tid & 7;
        bf16x8 v0 = *(const bf16x8*)&z2bf[n2][kg * 16];
        bf16x8 v1 = *(const bf16x8*)&z2bf[n2][kg * 16 + 8];
        float s = 0.f;
        #pragma unroll
        for (int j = 0; j < 8; ++j)
            s += (float)v0[j] * w3[kg * 16 + j] + (float)v1[j] * w3[kg * 16 + 8 + j];
        s += __shfl_xor(s, 1); s += __shfl_xor(s, 2); s += __shfl_xor(s, 4);
        if (kg == 0) out[(b0 + (n2 >> 5)) * 32 + (n2 & 31)] = sigf(s + b3[0]);
    }
}

extern "C" void kernel_launch(void* const* d_in, const int* in_sizes, int n_in,
                              void* d_out, int out_size, void* d_ws, size_t ws_size,
                              hipStream_t stream) {
    (void)in_sizes; (void)n_in; (void)d_ws; (void)ws_size; (void)out_size;
    const float* x     = (const float*)d_in[0];
    const float* dmat  = (const float*)d_in[1];
    const float* bmat  = (const float*)d_in[2];
    const float* hmat  = (const float*)d_in[3];
    const float* mask  = (const float*)d_in[4];
    const float* emb_w = (const float*)d_in[5];
    const float* emb_b = (const float*)d_in[6];
    const float* w_ih  = (const float*)d_in[7];
    const float* w_hh  = (const float*)d_in[8];
    const float* b_ih  = (const float*)d_in[9];
    const float* b_hh  = (const float*)d_in[10];
    const float* e2a_w = (const float*)d_in[11];
    const float* e2a_b = (const float*)d_in[12];
    const float* dom   = (const float*)d_in[13];
    const float* sp_w  = (const float*)d_in[14];
    const float* sp_b  = (const float*)d_in[15];
    const float* a2e_w = (const float*)d_in[16];
    const float* a2e_b = (const float*)d_in[17];
    const float* w1    = (const float*)d_in[18];
    const float* b1    = (const float*)d_in[19];
    const float* w2    = (const float*)d_in[20];
    const float* b2    = (const float*)d_in[21];
    const float* w3    = (const float*)d_in[22];
    const float* b3    = (const float*)d_in[23];
    float* out = (float*)d_out;

    traj_disc_kernel<<<dim3(256), dim3(512), 0, stream>>>(
        x, dmat, bmat, hmat, mask, emb_w, emb_b, w_ih, w_hh, b_ih, b_hh,
        e2a_w, e2a_b, dom, sp_w, sp_b, a2e_w, a2e_b,
        w1, b1, w2, b2, w3, b3, out);
}

// Round 7
// 77.900 us; speedup vs baseline: 1.0317x; 1.0317x over previous
//
#include <hip/hip_runtime.h>
#include <hip/hip_bf16.h>

#define TD_B 512

typedef __bf16 bf16x8 __attribute__((ext_vector_type(8)));
typedef __bf16 bf16x4 __attribute__((ext_vector_type(4)));
typedef float  f32x4  __attribute__((ext_vector_type(4)));

#define MFMA(a, b, c) __builtin_amdgcn_mfma_f32_16x16x32_bf16((a), (b), (c), 0, 0, 0)

__device__ __forceinline__ float sigf(float x)  { return 1.0f / (1.0f + __expf(-x)); }
__device__ __forceinline__ float tanhf_(float x){ return 2.0f / (1.0f + __expf(-2.0f * x)) - 1.0f; }

extern "C" __global__ void __launch_bounds__(256, 2)
traj_disc_kernel(const float* __restrict__ x, const float* __restrict__ dmat,
                 const float* __restrict__ bmat, const float* __restrict__ hmat,
                 const float* __restrict__ mask,
                 const float* __restrict__ emb_w, const float* __restrict__ emb_b,
                 const float* __restrict__ w_ih, const float* __restrict__ w_hh,
                 const float* __restrict__ b_ih, const float* __restrict__ b_hh,
                 const float* __restrict__ e2a_w, const float* __restrict__ e2a_b,
                 const float* __restrict__ dom,
                 const float* __restrict__ sp_w, const float* __restrict__ sp_b,
                 const float* __restrict__ a2e_w, const float* __restrict__ a2e_b,
                 const float* __restrict__ w1, const float* __restrict__ b1,
                 const float* __restrict__ w2, const float* __restrict__ b2,
                 const float* __restrict__ w3, const float* __restrict__ b3,
                 float* __restrict__ out)
{
    const int b    = blockIdx.x;
    const int tid  = threadIdx.x;
    const int lane = tid & 63;
    const int w    = tid >> 6;       // wave 0..3
    const int l15  = lane & 15;
    const int lg   = lane >> 4;      // 0..3

    __shared__ __bf16 sAin[32][72];   // 0-15 xe | 16-47 h | 48 ones | 49-63 zero
    __shared__ __bf16 sHl [32][40];
    __shared__ __bf16 sWN [32][40];
    __shared__ __bf16 sHaT[32][40];
    __shared__ __bf16 sEmb[32][40];
    __shared__ __bf16 sPA [32][72];   // 0-31 ha | 32-63 att
    __shared__ float  sMaskT[20][36];
    __shared__ float  sDom[144];
    __shared__ __bf16 z1bf[32][136];
    __shared__ __bf16 z2bf[32][136];

    // ---- staging ----
    for (int idx = tid; idx < 32 * 72; idx += 256)
        (&sAin[0][0])[idx] = (idx % 72 == 48) ? (__bf16)1.0f : (__bf16)0.0f;
    for (int idx = tid; idx < 640; idx += 256) {
        int tt = idx >> 5, n = idx & 31;
        sMaskT[tt][n] = mask[(b * 32 + n) * 20 + tt];
    }
    if (tid < 144) sDom[tid] = dom[tid];

    // phase-A per-thread constants
    const int i0 = tid >> 3, p0 = tid & 7;
    const float ewa0 = emb_w[2 * p0],      ewa1 = emb_w[2 * p0 + 1];
    const float ewb0 = emb_w[16 + 2 * p0], ewb1 = emb_w[16 + 2 * p0 + 1];
    const float eb0  = emb_b[2 * p0],      eb1  = emb_b[2 * p0 + 1];

    // ---- transposed-gates A-fragments (gate-interleaved cols c=4h+g) ----
    bf16x8 Ag[2][2];
    #pragma unroll
    for (int mtl = 0; mtl < 2; ++mtl) {
        int c  = (2 * w + mtl) * 16 + l15;
        int cg = (c & 3) * 32 + (c >> 2);
        #pragma unroll
        for (int kt = 0; kt < 2; ++kt)
            #pragma unroll
            for (int j = 0; j < 8; ++j) {
                int k = kt * 32 + lg * 8 + j;
                float v;
                if (k < 16)       v = w_ih[k * 128 + cg];
                else if (k < 48)  v = w_hh[(k - 16) * 128 + cg];
                else if (k == 48) v = b_ih[cg] + b_hh[cg];
                else              v = 0.0f;
                Ag[mtl][kt][j] = (__bf16)v;
            }
    }
    // wave roles for CD/EF: row-half mtw, col-half ntw
    const int mtw = w >> 1, ntw = w & 1;
    const int cw  = ntw * 16 + l15;
    bf16x8 Be2a, Ba2e, Bsp[2][2];
    #pragma unroll
    for (int j = 0; j < 8; ++j) {
        Be2a[j] = (__bf16)e2a_w[(lg * 8 + j) * 32 + cw];
        Ba2e[j] = (__bf16)a2e_w[(lg * 8 + j) * 32 + cw];
    }
    #pragma unroll
    for (int kt = 0; kt < 2; ++kt)
        #pragma unroll
        for (int nt2 = 0; nt2 < 2; ++nt2)
            #pragma unroll
            for (int j = 0; j < 8; ++j)
                Bsp[kt][nt2][j] = (__bf16)sp_w[(kt * 32 + lg * 8 + j) * 32 + nt2 * 16 + l15];
    const float bEw = e2a_b[cw], bAw = a2e_b[cw];
    const float bS2[2] = { sp_b[l15], sp_b[16 + l15] };

    float cst[2][2] = {{0.f, 0.f}, {0.f, 0.f}};  // cell state [mtl][nt], lane-local
    f32x4 accZ[2][2] = {};                       // online z1 [mt][ntp]
    bf16x8 Bw1cur[2];

    // prefetch t=0 inputs
    float4 pdv, pbv, phv; float px0, px1;
    {
        int base = ((b * 32 + i0) * 20 + 0) * 32 + 4 * p0;
        pdv = *(const float4*)(dmat + base);
        pbv = *(const float4*)(bmat + base);
        phv = *(const float4*)(hmat + base);
        int xb = ((b * 32 + i0) * 20 + 0) * 2;
        px0 = x[xb]; px1 = x[xb + 1];
    }
    __syncthreads();

    #pragma unroll 1
    for (int t = 0; t < 20; ++t) {
        // ===== phase A: wmat+normalize (regs), wN/xe stores; prefetch t+1 =====
        {
            float4 dv = pdv, bv = pbv, hv = phv;
            float xx0 = px0, xx1 = px1;
            if (t < 19) {
                int base = ((b * 32 + i0) * 20 + (t + 1)) * 32 + 4 * p0;
                pdv = *(const float4*)(dmat + base);
                pbv = *(const float4*)(bmat + base);
                phv = *(const float4*)(hmat + base);
                int xb = ((b * 32 + i0) * 20 + (t + 1)) * 2;
                px0 = x[xb]; px1 = x[xb + 1];
            }
            float4 mj = *(const float4*)&sMaskT[t][4 * p0];
            float  mi = sMaskT[t][i0];
            float wq[4];
            #pragma unroll
            for (int q = 0; q < 4; ++q) {
                float bq = (&bv.x)[q], hq = (&hv.x)[q];
                int ib = (int)floorf(bq * (1.0f / 30.0f)); ib = ib < 0 ? 0 : (ib > 11 ? 11 : ib);
                int ih = (int)floorf(hq * (1.0f / 30.0f)); ih = ih < 0 ? 0 : (ih > 11 ? 11 : ih);
                float v = sDom[ib * 12 + ih] - (&dv.x)[q];
                v = v > 0.f ? v : 0.f;
                wq[q] = v * (&mj.x)[q];
            }
            float s = wq[0] + wq[1] + wq[2] + wq[3];
            s += __shfl_xor(s, 1); s += __shfl_xor(s, 2); s += __shfl_xor(s, 4);
            float inv = mi / (mi * s + 1e-8f);
            bf16x4 wn4;
            #pragma unroll
            for (int q = 0; q < 4; ++q) wn4[q] = (__bf16)(wq[q] * inv);
            *(bf16x4*)&sWN[i0][4 * p0] = wn4;
            sAin[i0][2 * p0]     = (__bf16)(xx0 * ewa0 + xx1 * ewb0 + eb0);
            sAin[i0][2 * p0 + 1] = (__bf16)(xx0 * ewa1 + xx1 * ewb1 + eb1);
        }
        __syncthreads();                                   // s1

        // ===== phase B: transposed gates + lane-local cell + online z1 + w1 stream =====
        {
            bf16x8 bxh[2][2];
            #pragma unroll
            for (int nt = 0; nt < 2; ++nt)
                #pragma unroll
                for (int kt = 0; kt < 2; ++kt)
                    bxh[nt][kt] = *(const bf16x8*)&sAin[nt * 16 + l15][kt * 32 + lg * 8];
            if (t >= 1) {     // z1 += h_{t-1} @ w1[(t-1)*32:]
                bf16x8 az[2];
                #pragma unroll
                for (int mt = 0; mt < 2; ++mt)
                    az[mt] = *(const bf16x8*)&sAin[mt * 16 + l15][16 + lg * 8];
                #pragma unroll
                for (int mt = 0; mt < 2; ++mt)
                    #pragma unroll
                    for (int ntp = 0; ntp < 2; ++ntp)
                        accZ[mt][ntp] = MFMA(az[mt], Bw1cur[ntp], accZ[mt][ntp]);
            }
            #pragma unroll
            for (int mtl = 0; mtl < 2; ++mtl)
                #pragma unroll
                for (int nt = 0; nt < 2; ++nt) {
                    f32x4 cc = {0.f, 0.f, 0.f, 0.f};
                    cc = MFMA(Ag[mtl][0], bxh[nt][0], cc);
                    cc = MFMA(Ag[mtl][1], bxh[nt][1], cc);
                    float cn = sigf(cc[1]) * cst[mtl][nt] + sigf(cc[0]) * tanhf_(cc[2]);
                    cst[mtl][nt] = cn;
                    sHl[nt * 16 + l15][4 * (2 * w + mtl) + lg] = (__bf16)(sigf(cc[3]) * tanhf_(cn));
                }
            #pragma unroll
            for (int ntp = 0; ntp < 2; ++ntp) {   // stream w1 rows t*32..
                int c = (2 * w + ntp) * 16 + l15;
                #pragma unroll
                for (int j = 0; j < 8; ++j)
                    Bw1cur[ntp][j] = (__bf16)w1[(t * 32 + lg * 8 + j) * 128 + c];
            }
        }
        __syncthreads();                                   // s2

        // ===== phase C+D fused: ha (both row halves of col cw, dup across mtw) then att =====
        {
            #pragma unroll
            for (int mt = 0; mt < 2; ++mt) {
                bf16x8 a = *(const bf16x8*)&sHl[mt * 16 + l15][lg * 8];
                f32x4 cc = {0.f, 0.f, 0.f, 0.f};
                cc = MFMA(a, Be2a, cc);
                bf16x4 tv;
                #pragma unroll
                for (int q = 0; q < 4; ++q) {
                    float v = cc[q] + bEw;
                    tv[q] = (__bf16)v;
                    sPA[mt * 16 + 4 * lg + q][cw] = (__bf16)v;
                }
                *(bf16x4*)&sHaT[cw][mt * 16 + 4 * lg] = tv;
            }
            // att tile (mtw,ntw): haT rows written by this wave (in-order LDS)
            bf16x8 aW = *(const bf16x8*)&sWN [mtw * 16 + l15][lg * 8];
            bf16x8 bT = *(const bf16x8*)&sHaT[ntw * 16 + l15][lg * 8];
            f32x4 cc = {0.f, 0.f, 0.f, 0.f};
            cc = MFMA(aW, bT, cc);
            #pragma unroll
            for (int q = 0; q < 4; ++q)
                sPA[mtw * 16 + 4 * lg + q][32 + cw] = (__bf16)cc[q];
        }
        __syncthreads();                                   // s3

        // ===== phase E+F fused: emb row-stripe (both col halves, dup across ntw) then h_new =====
        {
            bf16x8 a0 = *(const bf16x8*)&sPA[mtw * 16 + l15][lg * 8];
            bf16x8 a1 = *(const bf16x8*)&sPA[mtw * 16 + l15][32 + lg * 8];
            #pragma unroll
            for (int nt2 = 0; nt2 < 2; ++nt2) {
                f32x4 cc = {0.f, 0.f, 0.f, 0.f};
                cc = MFMA(a0, Bsp[0][nt2], cc);
                cc = MFMA(a1, Bsp[1][nt2], cc);
                #pragma unroll
                for (int q = 0; q < 4; ++q)
                    sEmb[mtw * 16 + 4 * lg + q][nt2 * 16 + l15] = (__bf16)tanhf_(cc[q] + bS2[nt2]);
            }
            bf16x8 ae = *(const bf16x8*)&sEmb[mtw * 16 + l15][lg * 8];
            f32x4 cf = {0.f, 0.f, 0.f, 0.f};
            cf = MFMA(ae, Ba2e, cf);
            #pragma unroll
            for (int q = 0; q < 4; ++q)
                sAin[mtw * 16 + 4 * lg + q][16 + cw] = (__bf16)(cf[q] + bAw);
        }
        // no barrier: next-iteration s1 orders EF -> B(t+1); A(t+1) touches disjoint LDS
    }

    // ================= tail =================
    __syncthreads();
    // final z1 accumulate (h_19 with w1 rows 608-639)
    {
        bf16x8 az[2];
        #pragma unroll
        for (int mt = 0; mt < 2; ++mt)
            az[mt] = *(const bf16x8*)&sAin[mt * 16 + l15][16 + lg * 8];
        #pragma unroll
        for (int mt = 0; mt < 2; ++mt)
            #pragma unroll
            for (int ntp = 0; ntp < 2; ++ntp)
                accZ[mt][ntp] = MFMA(az[mt], Bw1cur[ntp], accZ[mt][ntp]);
    }
    // z1 = leaky(accZ + b1)
    #pragma unroll
    for (int mt = 0; mt < 2; ++mt)
        #pragma unroll
        for (int ntp = 0; ntp < 2; ++ntp) {
            int c = (2 * w + ntp) * 16 + l15;
            float bias = b1[c];
            #pragma unroll
            for (int q = 0; q < 4; ++q) {
                float v = accZ[mt][ntp][q] + bias;
                v = v > 0.f ? v : 0.2f * v;
                z1bf[mt * 16 + 4 * lg + q][c] = (__bf16)v;
            }
        }
    __syncthreads();

    // z2 = leaky(z1 @ w2 + b2), K=128
    {
        f32x4 c2[2][2] = {};
        #pragma unroll
        for (int kt = 0; kt < 4; ++kt) {
            bf16x8 a[2];
            #pragma unroll
            for (int mt = 0; mt < 2; ++mt)
                a[mt] = *(const bf16x8*)&z1bf[mt * 16 + l15][kt * 32 + lg * 8];
            bf16x8 bb[2];
            #pragma unroll
            for (int ntp = 0; ntp < 2; ++ntp) {
                int c = (2 * w + ntp) * 16 + l15;
                #pragma unroll
                for (int j = 0; j < 8; ++j)
                    bb[ntp][j] = (__bf16)w2[(kt * 32 + lg * 8 + j) * 128 + c];
            }
            #pragma unroll
            for (int mt = 0; mt < 2; ++mt)
                #pragma unroll
                for (int ntp = 0; ntp < 2; ++ntp)
                    c2[mt][ntp] = MFMA(a[mt], bb[ntp], c2[mt][ntp]);
        }
        #pragma unroll
        for (int mt = 0; mt < 2; ++mt)
            #pragma unroll
            for (int ntp = 0; ntp < 2; ++ntp) {
                int c = (2 * w + ntp) * 16 + l15;
                float bias = b2[c];
                #pragma unroll
                for (int q = 0; q < 4; ++q) {
                    float v = c2[mt][ntp][q] + bias;
                    v = v > 0.f ? v : 0.2f * v;
                    z2bf[mt * 16 + 4 * lg + q][c] = (__bf16)v;
                }
            }
    }
    __syncthreads();

    // z3 = sigmoid(z2 @ w3 + b3)
    {
        int n = tid >> 3, kg = tid & 7;
        bf16x8 v0 = *(const bf16x8*)&z2bf[n][kg * 16];
        bf16x8 v1 = *(const bf16x8*)&z2bf[n][kg * 16 + 8];
        float s = 0.f;
        #pragma unroll
        for (int j = 0; j < 8; ++j)
            s += (float)v0[j] * w3[kg * 16 + j] + (float)v1[j] * w3[kg * 16 + 8 + j];
        s += __shfl_xor(s, 1); s += __shfl_xor(s, 2); s += __shfl_xor(s, 4);
        if (kg == 0) out[b * 32 + n] = sigf(s + b3[0]);
    }
}

extern "C" void kernel_launch(void* const* d_in, const int* in_sizes, int n_in,
                              void* d_out, int out_size, void* d_ws, size_t ws_size,
                              hipStream_t stream) {
    (void)in_sizes; (void)n_in; (void)d_ws; (void)ws_size; (void)out_size;
    const float* x     = (const float*)d_in[0];
    const float* dmat  = (const float*)d_in[1];
    const float* bmat  = (const float*)d_in[2];
    const float* hmat  = (const float*)d_in[3];
    const float* mask  = (const float*)d_in[4];
    const float* emb_w = (const float*)d_in[5];
    const float* emb_b = (const float*)d_in[6];
    const float* w_ih  = (const float*)d_in[7];
    const float* w_hh  = (const float*)d_in[8];
    const float* b_ih  = (const float*)d_in[9];
    const float* b_hh  = (const float*)d_in[10];
    const float* e2a_w = (const float*)d_in[11];
    const float* e2a_b = (const float*)d_in[12];
    const float* dom   = (const float*)d_in[13];
    const float* sp_w  = (const float*)d_in[14];
    const float* sp_b  = (const float*)d_in[15];
    const float* a2e_w = (const float*)d_in[16];
    const float* a2e_b = (const float*)d_in[17];
    const float* w1    = (const float*)d_in[18];
    const float* b1    = (const float*)d_in[19];
    const float* w2    = (const float*)d_in[20];
    const float* b2    = (const float*)d_in[21];
    const float* w3    = (const float*)d_in[22];
    const float* b3    = (const float*)d_in[23];
    float* out = (float*)d_out;

    traj_disc_kernel<<<dim3(TD_B), dim3(256), 0, stream>>>(
        x, dmat, bmat, hmat, mask, emb_w, emb_b, w_ih, w_hh, b_ih, b_hh,
        e2a_w, e2a_b, dom, sp_w, sp_b, a2e_w, a2e_b,
        w1, b1, w2, b2, w3, b3, out);
}